// Round 2
// baseline (6514.059 us; speedup 1.0000x reference)
//
#include <hip/hip_runtime.h>
#include <hip/hip_bf16.h>
#include <math.h>

// Problem dims (fixed by reference): T=2, B=16, L=2048, D=512, G=1024
#define TT 2
#define BB 16
#define LL 2048
#define NN 4096   // T*L
#define DD 512
#define GG 1024
#define SCALE 0.044194173824159216f   // 1/sqrt(512)

// inv_pos(d) = 10000^(-(d>>1)/256) = 2^(-log2(10000)/256 * (d>>1))
__device__ __forceinline__ float inv_pos_f(int d) {
    return exp2f(-0.051905126482615036f * (float)(d >> 1));
}

// ---------------- q table: q[g][d] = sinusoid((g+0.5)/pos[d]) ----------------
__global__ void qgrid_kernel(float* __restrict__ qbuf) {
    const int g = blockIdx.x;
    const int tid = threadIdx.x;  // 128
    const float mid = (float)g + 0.5f;
#pragma unroll
    for (int i = 0; i < 4; ++i) {
        int d = i * 128 + tid;
        float theta = mid * inv_pos_f(d);
        float v = (d & 1) ? cosf(theta) : sinf(theta);
        qbuf[(size_t)g * DD + d] = v;
    }
}

// ---------------- emb table: emb[b][n][d] (bf16), n = t*L + l ----------------
__global__ void emb_kernel(const float* __restrict__ times,
                           const float* __restrict__ type_emb,
                           __hip_bfloat16* __restrict__ emb) {
    const int row = blockIdx.x;            // b*NN + n
    const int b = row >> 12;
    const int n = row & (NN - 1);
    const int t = n >> 11;
    const int l = n & (LL - 1);
    const float tm = times[(size_t)(t * BB + b) * LL + l];
    const float pad = (tm != 0.0f) ? 1.0f : 0.0f;
    const int tid = threadIdx.x;           // 256
#pragma unroll
    for (int i = 0; i < 2; ++i) {
        int d = i * 256 + tid;
        float theta = tm * inv_pos_f(d);
        float v = (d & 1) ? cosf(theta) : sinf(theta);
        v = (v + type_emb[t * DD + d]) * pad;
        emb[(size_t)row * DD + d] = __float2bfloat16(v);
    }
}

// ---------------- fused attention: one block per (b,g) ----------------
__global__ void attn_kernel(const __hip_bfloat16* __restrict__ emb,
                            const float* __restrict__ qbuf,
                            const int* __restrict__ real_len,
                            float* __restrict__ out) {
    __shared__ float s_lds[NN];    // scores -> softmax weights -> partial sums
    __shared__ float q_s[DD];
    __shared__ float red[8];

    const int blk = blockIdx.x;
    const int b = blk >> 10;
    const int g = blk & (GG - 1);
    const int tid = threadIdx.x;   // 256
    const int lane = tid & 63;
    const int wave = tid >> 6;

    q_s[tid]       = qbuf[(size_t)g * DD + tid];
    q_s[tid + 256] = qbuf[(size_t)g * DD + tid + 256];
    __syncthreads();

    // lane's q chunk for phase 1: d = lane*8 + j
    float qr[8];
#pragma unroll
    for (int j = 0; j < 8; ++j) qr[j] = q_s[lane * 8 + j];

    const unsigned int* embB =
        reinterpret_cast<const unsigned int*>(emb) + (size_t)b * NN * (DD / 2);

    // -------- phase 1: scores. wave handles row n = it*4+wave, lane covers 8 d's
#pragma unroll 2
    for (int it = 0; it < NN / 4; ++it) {
        const int n = it * 4 + wave;
        const uint4 raw = *reinterpret_cast<const uint4*>(embB + (size_t)n * (DD / 2) + lane * 4);
        float s = 0.f;
        s = fmaf(__uint_as_float(raw.x << 16),         qr[0], s);
        s = fmaf(__uint_as_float(raw.x & 0xffff0000u), qr[1], s);
        s = fmaf(__uint_as_float(raw.y << 16),         qr[2], s);
        s = fmaf(__uint_as_float(raw.y & 0xffff0000u), qr[3], s);
        s = fmaf(__uint_as_float(raw.z << 16),         qr[4], s);
        s = fmaf(__uint_as_float(raw.z & 0xffff0000u), qr[5], s);
        s = fmaf(__uint_as_float(raw.w << 16),         qr[6], s);
        s = fmaf(__uint_as_float(raw.w & 0xffff0000u), qr[7], s);
#pragma unroll
        for (int off = 32; off; off >>= 1) s += __shfl_xor(s, off, 64);
        if (lane == 0) s_lds[n] = s * SCALE;
    }
    __syncthreads();

    // -------- phase 2: masked softmax over n
    const int rl0 = real_len[b];        // [T,B] flat: t=0 -> b
    const int rl1 = real_len[BB + b];   // t=1
    float m = -INFINITY;
    float sv[16];
#pragma unroll
    for (int i = 0; i < 16; ++i) {
        const int n = i * 256 + tid;
        float s = s_lds[n];
        const int l = n & (LL - 1);
        const bool valid = l < ((n < LL) ? rl0 : rl1);
        s = valid ? s : -INFINITY;
        sv[i] = s;
        m = fmaxf(m, s);
    }
#pragma unroll
    for (int off = 32; off; off >>= 1) m = fmaxf(m, __shfl_xor(m, off, 64));
    if (lane == 0) red[wave] = m;
    __syncthreads();
    m = fmaxf(fmaxf(red[0], red[1]), fmaxf(red[2], red[3]));

    float lsum = 0.f;
#pragma unroll
    for (int i = 0; i < 16; ++i) {
        const int n = i * 256 + tid;
        const float e = expf(sv[i] - m);   // exp(-inf) = 0 for invalid
        s_lds[n] = e;
        lsum += e;
    }
#pragma unroll
    for (int off = 32; off; off >>= 1) lsum += __shfl_xor(lsum, off, 64);
    if (lane == 0) red[4 + wave] = lsum;
    __syncthreads();
    const float inv_l = 1.0f / (red[4] + red[5] + red[6] + red[7]);

    // -------- phase 3: out[d] = inv_l * sum_n p[n]*emb[n][d]
    // wave handles n ≡ wave (mod 4); lane owns d = lane*8 .. lane*8+7
    float acc[8] = {0.f, 0.f, 0.f, 0.f, 0.f, 0.f, 0.f, 0.f};
#pragma unroll 2
    for (int k = 0; k < NN / 4; ++k) {
        const int n = k * 4 + wave;
        const float p = s_lds[n];   // LDS broadcast (same addr per wave)
        const uint4 raw = *reinterpret_cast<const uint4*>(embB + (size_t)n * (DD / 2) + lane * 4);
        acc[0] = fmaf(p, __uint_as_float(raw.x << 16),         acc[0]);
        acc[1] = fmaf(p, __uint_as_float(raw.x & 0xffff0000u), acc[1]);
        acc[2] = fmaf(p, __uint_as_float(raw.y << 16),         acc[2]);
        acc[3] = fmaf(p, __uint_as_float(raw.y & 0xffff0000u), acc[3]);
        acc[4] = fmaf(p, __uint_as_float(raw.z << 16),         acc[4]);
        acc[5] = fmaf(p, __uint_as_float(raw.z & 0xffff0000u), acc[5]);
        acc[6] = fmaf(p, __uint_as_float(raw.w << 16),         acc[6]);
        acc[7] = fmaf(p, __uint_as_float(raw.w & 0xffff0000u), acc[7]);
    }
    __syncthreads();   // done reading p's; reuse s_lds for partials
    *reinterpret_cast<float4*>(&s_lds[wave * DD + lane * 8])     = make_float4(acc[0], acc[1], acc[2], acc[3]);
    *reinterpret_cast<float4*>(&s_lds[wave * DD + lane * 8 + 4]) = make_float4(acc[4], acc[5], acc[6], acc[7]);
    __syncthreads();

    {
        const int d0 = tid * 2;
        const float o0 = (s_lds[d0]     + s_lds[DD + d0]     + s_lds[2 * DD + d0]     + s_lds[3 * DD + d0])     * inv_l;
        const float o1 = (s_lds[d0 + 1] + s_lds[DD + d0 + 1] + s_lds[2 * DD + d0 + 1] + s_lds[3 * DD + d0 + 1]) * inv_l;
        float2 o2 = make_float2(o0, o1);
        *reinterpret_cast<float2*>(out + (size_t)blk * DD + d0) = o2;
    }
}

extern "C" void kernel_launch(void* const* d_in, const int* in_sizes, int n_in,
                              void* d_out, int out_size, void* d_ws, size_t ws_size,
                              hipStream_t stream) {
    const float* times    = (const float*)d_in[0];
    const float* type_emb = (const float*)d_in[1];
    const int*   real_len = (const int*)d_in[2];
    float* out = (float*)d_out;

    // ws layout: emb bf16 [B][N][D] = 64 MB, then q f32 [G][D] = 2 MB
    __hip_bfloat16* emb = (__hip_bfloat16*)d_ws;
    float* qbuf = (float*)((char*)d_ws + (size_t)BB * NN * DD * sizeof(__hip_bfloat16));

    qgrid_kernel<<<GG, 128, 0, stream>>>(qbuf);
    emb_kernel<<<BB * NN, 256, 0, stream>>>(times, type_emb, emb);
    attn_kernel<<<BB * GG, 256, 0, stream>>>(emb, qbuf, real_len, out);
}

// Round 3
// 474.511 us; speedup vs baseline: 13.7279x; 13.7279x over previous
//
#include <hip/hip_runtime.h>
#include <hip/hip_bf16.h>
#include <math.h>

// Problem dims (fixed by reference): T=2, B=16, L=2048, D=512, G=1024
#define TT 2
#define BB 16
#define LL 2048
#define NN 4096   // T*L
#define DD 512
#define GG 1024
#define SCALE 0.044194173824159216f   // 1/sqrt(512)
#define LOG2E 1.4426950408889634f
#define QSCL (SCALE * LOG2E)          // fold into q so scores are in log2 units

typedef unsigned short ushort_t;
typedef short short8 __attribute__((ext_vector_type(8)));   // 8 bf16 = 4 VGPR (MFMA A/B frag)
typedef float f32x4 __attribute__((ext_vector_type(4)));    // MFMA C/D frag

// inv_pos(d) = 10000^(-(d>>1)/256) = 2^(-log2(10000)/256 * (d>>1))
__device__ __forceinline__ float inv_pos_f(int d) {
    return exp2f(-0.051905126482615036f * (float)(d >> 1));
}
__device__ __forceinline__ unsigned short f2b(float f) {  // fp32 -> bf16 bits, RNE
    union { float f; unsigned u; } x; x.f = f;
    unsigned r = x.u + 0x7fffu + ((x.u >> 16) & 1u);
    return (unsigned short)(r >> 16);
}

// ---------------- q table (bf16, pre-scaled): q'[g][d] ----------------
__global__ void qb_kernel(ushort_t* __restrict__ qb) {
    const int g = blockIdx.x;
    const int tid = threadIdx.x;  // 128
    const float mid = (float)g + 0.5f;
#pragma unroll
    for (int i = 0; i < 4; ++i) {
        int d = i * 128 + tid;
        float theta = mid * inv_pos_f(d);
        float v = (d & 1) ? cosf(theta) : sinf(theta);
        qb[(size_t)g * DD + d] = f2b(v * QSCL);
    }
}

// ---------------- q table f32 (fallback path) ----------------
__global__ void qgrid_kernel(float* __restrict__ qbuf) {
    const int g = blockIdx.x;
    const int tid = threadIdx.x;  // 128
    const float mid = (float)g + 0.5f;
#pragma unroll
    for (int i = 0; i < 4; ++i) {
        int d = i * 128 + tid;
        float theta = mid * inv_pos_f(d);
        float v = (d & 1) ? cosf(theta) : sinf(theta);
        qbuf[(size_t)g * DD + d] = v;
    }
}

// ---------------- emb table: emb[b][n][d] (bf16 bits), n = t*L + l ----------------
__global__ void emb_kernel(const float* __restrict__ times,
                           const float* __restrict__ type_emb,
                           ushort_t* __restrict__ emb) {
    const int row = blockIdx.x;            // b*NN + n
    const int b = row >> 12;
    const int n = row & (NN - 1);
    const int t = n >> 11;
    const int l = n & (LL - 1);
    const float tm = times[(size_t)(t * BB + b) * LL + l];
    const float pad = (tm != 0.0f) ? 1.0f : 0.0f;
    const int tid = threadIdx.x;           // 256
#pragma unroll
    for (int i = 0; i < 2; ++i) {
        int d = i * 256 + tid;
        float theta = tm * inv_pos_f(d);
        float v = (d & 1) ? cosf(theta) : sinf(theta);
        v = (v + type_emb[t * DD + d]) * pad;
        emb[(size_t)row * DD + d] = f2b(v);
    }
}

// ---------------- embT[b][d][n] = emb[b][n][d] (64x64 LDS tile transpose) ----------------
__global__ void transpose_kernel(const ushort_t* __restrict__ emb,
                                 ushort_t* __restrict__ embT) {
    __shared__ ushort_t tile[64][80];      // row = n, 80*2=160B stride (16B-mult)
    const int bid = blockIdx.x;            // b*(64*8) + ntile*8 + dtile
    const int dt = bid & 7;                // DD/64 = 8
    const int ntl = (bid >> 3) & 63;       // NN/64 = 64
    const int b = bid >> 9;
    const int n0 = ntl * 64, d0 = dt * 64;
    const int tid = threadIdx.x;           // 256
    const int r = tid >> 3;                // 0..31
    const int c8 = (tid & 7) * 8;
#pragma unroll
    for (int i = 0; i < 2; ++i) {
        const int row = r + i * 32;
        short8 v = *reinterpret_cast<const short8*>(
            emb + ((size_t)(b * NN + n0 + row)) * DD + d0 + c8);
        *reinterpret_cast<short8*>(&tile[row][c8]) = v;
    }
    __syncthreads();
#pragma unroll
    for (int i = 0; i < 2; ++i) {
        const int dr = r + i * 32;
        short8 ov;
#pragma unroll
        for (int j = 0; j < 8; ++j) ov[j] = (short)tile[c8 + j][dr];
        *reinterpret_cast<short8*>(
            embT + ((size_t)(b * DD + d0 + dr)) * NN + n0 + c8) = ov;
    }
}

// ---------------- flash attention: one block per (b, 32-g tile) ----------------
// GEMM1: S[32n][32g] = embA_tile * q'^T (K=512), 4 waves x one 16x16 tile
// online softmax over n (cols = g), P in LDS [g][n] bf16
// GEMM2: O^T[512d][32g] += embT(global) * P, per wave 8 d-tiles x 2 g-tiles
__global__ __launch_bounds__(256, 2)
void attn_flash(const ushort_t* __restrict__ emb,
                const ushort_t* __restrict__ embT,
                const ushort_t* __restrict__ qb,
                const int* __restrict__ real_len,
                float* __restrict__ out) {
    __shared__ __align__(16) ushort_t sA[32 * 520];  // emb tile, row stride 1040B (pad +16B)
    __shared__ __align__(16) ushort_t sP[32 * 40];   // P [g][n], row stride 80B (pad +16B)
    __shared__ float s_cmax[2][32];
    __shared__ float s_psum[2][32];
    __shared__ float s_m[32];
    __shared__ float s_l[32];

    const int idx = blockIdx.x;               // swizzle: idx%8 = XCD = b%8 (L2 locality)
    const int xcd = idx & 7;
    const int slot = idx >> 3;                // 0..63
    const int b = xcd + ((slot >> 5) << 3);
    const int gt = slot & 31;
    const int g0 = gt * 32;

    const int tid = threadIdx.x;              // 256
    const int lane = tid & 63;
    const int w = tid >> 6;                   // 4 waves
    const int l15 = lane & 15;
    const int quad = lane >> 4;               // 0..3
    const int mt1 = w >> 1;                   // GEMM1 n-tile (0/1)
    const int gt1 = w & 1;                    // GEMM1 g-tile (0/1)

    if (tid < 32) { s_m[tid] = -INFINITY; s_l[tid] = 0.f; }

    // q B-fragments resident in registers: B[k=d][g]; lane holds q'[g][kc*32+quad*8+j]
    short8 qf[16];
    {
        const ushort_t* qrow = qb + (size_t)(g0 + gt1 * 16 + l15) * DD + quad * 8;
#pragma unroll
        for (int kc = 0; kc < 16; ++kc)
            qf[kc] = *reinterpret_cast<const short8*>(qrow + kc * 32);
    }

    const ushort_t* embB  = emb  + (size_t)b * NN * DD;
    const ushort_t* embTB = embT + (size_t)b * DD * NN;

    const int rl0 = real_len[b];              // [T][B] flat
    const int rl1 = real_len[BB + b];
    const int e0 = (rl0 + 31) >> 5;           // valid 32-n tiles in t=0 half
    const int e1 = 64 + ((rl1 + 31) >> 5);    // t=1 half starts at tile 64
    const int total = e0 + (e1 - 64);         // ragged skip: avg ~half the 128 tiles

    f32x4 accO[8][2];
#pragma unroll
    for (int i = 0; i < 8; ++i) { accO[i][0] = (f32x4)0.f; accO[i][1] = (f32x4)0.f; }

    // async stage one 32x512 emb tile; wave stages rows w*8..w*8+7 (1 row = 1KB = 1 inst)
    auto stage = [&](int nt) {
        const ushort_t* src = embB + (size_t)(nt * 32 + w * 8) * DD + lane * 8;
        ushort_t* dst = sA + (w * 8) * 520;
#pragma unroll
        for (int i = 0; i < 8; ++i) {
            __builtin_amdgcn_global_load_lds(
                (const __attribute__((address_space(1))) unsigned int*)(src + (size_t)i * DD),
                (__attribute__((address_space(3))) unsigned int*)(dst + i * 520),
                16, 0, 0);
        }
    };

    int cur = 0;
    stage(0);

    for (int it = 0; it < total; ++it) {
        const int nxt = (cur + 1 == e0) ? 64 : cur + 1;
        __syncthreads();   // B1: staging drained (vmcnt), prev P-reads done

        // ---- GEMM1: S tile (rows n = mt1*16+quad*4+r, cols g = gt1*16+l15)
        f32x4 S = (f32x4)0.f;
        {
            const ushort_t* arow = sA + (mt1 * 16 + l15) * 520 + quad * 8;
#pragma unroll
            for (int kc = 0; kc < 16; ++kc) {
                short8 a = *reinterpret_cast<const short8*>(arow + kc * 32);
                S = __builtin_amdgcn_mfma_f32_16x16x32_bf16(a, qf[kc], S, 0, 0, 0);
            }
        }

        // ---- validity mask + column max (reduce over n = lane quads + mt pairs)
        const int n0 = cur * 32;
        const int nb = n0 + mt1 * 16 + quad * 4;
        const int rl = (nb >= LL) ? rl1 : rl0;
        const int lb = nb & (LL - 1);
        float sv[4];
#pragma unroll
        for (int r = 0; r < 4; ++r)
            sv[r] = (lb + r < rl) ? S[r] : -INFINITY;
        float cm = fmaxf(fmaxf(sv[0], sv[1]), fmaxf(sv[2], sv[3]));
        cm = fmaxf(cm, __shfl_xor(cm, 16, 64));
        cm = fmaxf(cm, __shfl_xor(cm, 32, 64));
        if (lane < 16) s_cmax[mt1][gt1 * 16 + lane] = cm;
        __syncthreads();  // B2: cmax ready

        // ---- new max / alpha; rescale O (skip when alpha==1 everywhere); P = exp2
        const float mo0 = s_m[l15], mo1 = s_m[16 + l15];
        const float mn0 = fmaxf(mo0, fmaxf(s_cmax[0][l15], s_cmax[1][l15]));
        const float mn1 = fmaxf(mo1, fmaxf(s_cmax[0][16 + l15], s_cmax[1][16 + l15]));
        const float al0 = exp2f(mo0 - mn0);
        const float al1 = exp2f(mo1 - mn1);
        if (__any((al0 < 1.f) || (al1 < 1.f))) {
#pragma unroll
            for (int i = 0; i < 8; ++i)
#pragma unroll
                for (int r = 0; r < 4; ++r) { accO[i][0][r] *= al0; accO[i][1][r] *= al1; }
        }
        const float mnP = gt1 ? mn1 : mn0;
        const float p0 = exp2f(sv[0] - mnP), p1 = exp2f(sv[1] - mnP);
        const float p2 = exp2f(sv[2] - mnP), p3 = exp2f(sv[3] - mnP);
        {
            union { unsigned short us[4]; unsigned long long u64; } pk;
            pk.us[0] = f2b(p0); pk.us[1] = f2b(p1); pk.us[2] = f2b(p2); pk.us[3] = f2b(p3);
            *reinterpret_cast<unsigned long long*>(
                sP + (gt1 * 16 + l15) * 40 + mt1 * 16 + quad * 4) = pk.u64;
        }
        float ps = (p0 + p1) + (p2 + p3);
        ps += __shfl_xor(ps, 16, 64);
        ps += __shfl_xor(ps, 32, 64);
        if (lane < 16) s_psum[mt1][gt1 * 16 + lane] = ps;
        __syncthreads();  // B3: P & psum ready; embA reads done (pre-B2)

        if (w == 0 && lane < 32) {   // exactly-once stats update
            const float mo = s_m[lane];
            const float mn = fmaxf(mo, fmaxf(s_cmax[0][lane], s_cmax[1][lane]));
            s_l[lane] = s_l[lane] * exp2f(mo - mn) + s_psum[0][lane] + s_psum[1][lane];
            s_m[lane] = mn;
        }

        if (it + 1 < total) stage(nxt);   // overlap DMA with GEMM2

        // ---- GEMM2: A = embT direct from global (16B/lane, 64B-coalesced), B = P (LDS)
        {
            const ushort_t* trow = embTB + (size_t)(w * 128 + l15) * NN + n0 + quad * 8;
            short8 bP0 = *reinterpret_cast<const short8*>(sP + l15 * 40 + quad * 8);
            short8 bP1 = *reinterpret_cast<const short8*>(sP + (16 + l15) * 40 + quad * 8);
#pragma unroll
            for (int mt = 0; mt < 8; ++mt) {
                short8 a = *reinterpret_cast<const short8*>(trow + (size_t)mt * 16 * NN);
                accO[mt][0] = __builtin_amdgcn_mfma_f32_16x16x32_bf16(a, bP0, accO[mt][0], 0, 0, 0);
                accO[mt][1] = __builtin_amdgcn_mfma_f32_16x16x32_bf16(a, bP1, accO[mt][1], 0, 0, 0);
            }
        }
        cur = nxt;
    }

    __syncthreads();   // stats final
    const float il0 = 1.f / s_l[l15];
    const float il1 = 1.f / s_l[16 + l15];
#pragma unroll
    for (int mt = 0; mt < 8; ++mt) {
#pragma unroll
        for (int gtt = 0; gtt < 2; ++gtt) {
            const float il = gtt ? il1 : il0;
            float4 v;
            v.x = accO[mt][gtt][0] * il;
            v.y = accO[mt][gtt][1] * il;
            v.z = accO[mt][gtt][2] * il;
            v.w = accO[mt][gtt][3] * il;
            const int g = g0 + gtt * 16 + l15;
            const int d = w * 128 + mt * 16 + quad * 4;
            *reinterpret_cast<float4*>(out + ((size_t)b * GG + g) * DD + d) = v;
        }
    }
}

// ---------------- fallback attention (round-2 proven path, used if ws too small) ----------------
__global__ void attn_kernel(const ushort_t* __restrict__ emb,
                            const float* __restrict__ qbuf,
                            const int* __restrict__ real_len,
                            float* __restrict__ out) {
    __shared__ float s_lds[NN];
    __shared__ float q_s[DD];
    __shared__ float red[8];

    const int blk = blockIdx.x;
    const int b = blk >> 10;
    const int g = blk & (GG - 1);
    const int tid = threadIdx.x;   // 256
    const int lane = tid & 63;
    const int wave = tid >> 6;

    q_s[tid]       = qbuf[(size_t)g * DD + tid];
    q_s[tid + 256] = qbuf[(size_t)g * DD + tid + 256];
    __syncthreads();

    float qr[8];
#pragma unroll
    for (int j = 0; j < 8; ++j) qr[j] = q_s[lane * 8 + j];

    const unsigned int* embB =
        reinterpret_cast<const unsigned int*>(emb) + (size_t)b * NN * (DD / 2);

#pragma unroll 2
    for (int it = 0; it < NN / 4; ++it) {
        const int n = it * 4 + wave;
        const uint4 raw = *reinterpret_cast<const uint4*>(embB + (size_t)n * (DD / 2) + lane * 4);
        float s = 0.f;
        s = fmaf(__uint_as_float(raw.x << 16),         qr[0], s);
        s = fmaf(__uint_as_float(raw.x & 0xffff0000u), qr[1], s);
        s = fmaf(__uint_as_float(raw.y << 16),         qr[2], s);
        s = fmaf(__uint_as_float(raw.y & 0xffff0000u), qr[3], s);
        s = fmaf(__uint_as_float(raw.z << 16),         qr[4], s);
        s = fmaf(__uint_as_float(raw.z & 0xffff0000u), qr[5], s);
        s = fmaf(__uint_as_float(raw.w << 16),         qr[6], s);
        s = fmaf(__uint_as_float(raw.w & 0xffff0000u), qr[7], s);
#pragma unroll
        for (int off = 32; off; off >>= 1) s += __shfl_xor(s, off, 64);
        if (lane == 0) s_lds[n] = s * SCALE;
    }
    __syncthreads();

    const int rl0 = real_len[b];
    const int rl1 = real_len[BB + b];
    float m = -INFINITY;
    float sv[16];
#pragma unroll
    for (int i = 0; i < 16; ++i) {
        const int n = i * 256 + tid;
        float s = s_lds[n];
        const int l = n & (LL - 1);
        const bool valid = l < ((n < LL) ? rl0 : rl1);
        s = valid ? s : -INFINITY;
        sv[i] = s;
        m = fmaxf(m, s);
    }
#pragma unroll
    for (int off = 32; off; off >>= 1) m = fmaxf(m, __shfl_xor(m, off, 64));
    if (lane == 0) red[wave] = m;
    __syncthreads();
    m = fmaxf(fmaxf(red[0], red[1]), fmaxf(red[2], red[3]));

    float lsum = 0.f;
#pragma unroll
    for (int i = 0; i < 16; ++i) {
        const int n = i * 256 + tid;
        const float e = expf(sv[i] - m);
        s_lds[n] = e;
        lsum += e;
    }
#pragma unroll
    for (int off = 32; off; off >>= 1) lsum += __shfl_xor(lsum, off, 64);
    if (lane == 0) red[4 + wave] = lsum;
    __syncthreads();
    const float inv_l = 1.0f / (red[4] + red[5] + red[6] + red[7]);

    float acc[8] = {0.f, 0.f, 0.f, 0.f, 0.f, 0.f, 0.f, 0.f};
#pragma unroll 2
    for (int k = 0; k < NN / 4; ++k) {
        const int n = k * 4 + wave;
        const float p = s_lds[n];
        const uint4 raw = *reinterpret_cast<const uint4*>(embB + (size_t)n * (DD / 2) + lane * 4);
        acc[0] = fmaf(p, __uint_as_float(raw.x << 16),         acc[0]);
        acc[1] = fmaf(p, __uint_as_float(raw.x & 0xffff0000u), acc[1]);
        acc[2] = fmaf(p, __uint_as_float(raw.y << 16),         acc[2]);
        acc[3] = fmaf(p, __uint_as_float(raw.y & 0xffff0000u), acc[3]);
        acc[4] = fmaf(p, __uint_as_float(raw.z << 16),         acc[4]);
        acc[5] = fmaf(p, __uint_as_float(raw.z & 0xffff0000u), acc[5]);
        acc[6] = fmaf(p, __uint_as_float(raw.w << 16),         acc[6]);
        acc[7] = fmaf(p, __uint_as_float(raw.w & 0xffff0000u), acc[7]);
    }
    __syncthreads();
    *reinterpret_cast<float4*>(&s_lds[wave * DD + lane * 8])     = make_float4(acc[0], acc[1], acc[2], acc[3]);
    *reinterpret_cast<float4*>(&s_lds[wave * DD + lane * 8 + 4]) = make_float4(acc[4], acc[5], acc[6], acc[7]);
    __syncthreads();

    {
        const int d0 = tid * 2;
        const float o0 = (s_lds[d0]     + s_lds[DD + d0]     + s_lds[2 * DD + d0]     + s_lds[3 * DD + d0])     * inv_l;
        const float o1 = (s_lds[d0 + 1] + s_lds[DD + d0 + 1] + s_lds[2 * DD + d0 + 1] + s_lds[3 * DD + d0 + 1]) * inv_l;
        *reinterpret_cast<float2*>(out + (size_t)blk * DD + d0) = make_float2(o0, o1);
    }
}

extern "C" void kernel_launch(void* const* d_in, const int* in_sizes, int n_in,
                              void* d_out, int out_size, void* d_ws, size_t ws_size,
                              hipStream_t stream) {
    const float* times    = (const float*)d_in[0];
    const float* type_emb = (const float*)d_in[1];
    const int*   real_len = (const int*)d_in[2];
    float* out = (float*)d_out;

    ushort_t* emb = (ushort_t*)d_ws;
    const size_t embBytes = (size_t)BB * NN * DD * sizeof(ushort_t);       // 64 MB
    const size_t needFast = 2 * embBytes + (size_t)GG * DD * sizeof(ushort_t); // 129 MB

    emb_kernel<<<BB * NN, 256, 0, stream>>>(times, type_emb, emb);

    if (ws_size >= needFast) {
        ushort_t* embT = (ushort_t*)((char*)d_ws + embBytes);
        ushort_t* qb   = (ushort_t*)((char*)d_ws + 2 * embBytes);
        qb_kernel<<<GG, 128, 0, stream>>>(qb);
        transpose_kernel<<<BB * 64 * 8, 256, 0, stream>>>(emb, embT);
        attn_flash<<<BB * 32, 256, 0, stream>>>(emb, embT, qb, real_len, out);
    } else {
        // fallback: 66 MB footprint (proven in round 2)
        float* qbuf = (float*)((char*)d_ws + embBytes);
        qgrid_kernel<<<GG, 128, 0, stream>>>(qbuf);
        attn_kernel<<<BB * GG, 256, 0, stream>>>(emb, qbuf, real_len, out);
    }
}

// Round 4
// 350.103 us; speedup vs baseline: 18.6061x; 1.3553x over previous
//
#include <hip/hip_runtime.h>
#include <hip/hip_bf16.h>
#include <math.h>

// Problem dims (fixed by reference): T=2, B=16, L=2048, D=512, G=1024
#define TT 2
#define BB 16
#define LL 2048
#define NN 4096   // T*L
#define DD 512
#define GG 1024
#define SCALE 0.044194173824159216f   // 1/sqrt(512)
#define LOG2E 1.4426950408889634f
#define QSCL (SCALE * LOG2E)          // fold into q so scores are in log2 units
#define C_IP 0.051905126482615036f    // log2(10000)/256

typedef unsigned short ushort_t;
typedef short short8 __attribute__((ext_vector_type(8)));   // 8 bf16 = 4 VGPR (MFMA A/B frag)
typedef float f32x4 __attribute__((ext_vector_type(4)));    // MFMA C/D frag

__device__ __forceinline__ float inv_pos_f(int dhalf) {
    return exp2f(-C_IP * (float)dhalf);
}
__device__ __forceinline__ unsigned short f2b(float f) {  // fp32 -> bf16 bits, RNE
    union { float f; unsigned u; } x; x.f = f;
    unsigned r = x.u + 0x7fffu + ((x.u >> 16) & 1u);
    return (unsigned short)(r >> 16);
}

// ---------------- fused emb + embT generator ----------------
// grid: BB * 64 blocks (one per (b, 64-n tile)), 256 threads.
// Phase A writes emb[b][n][d] rows; phase B recomputes values in transposed
// order and writes embT[b][d][n] — no LDS transpose, no bank conflicts,
// fully coalesced 16B stores both ways. hw v_sin/v_cos (err ~8e-5 rad @
// theta<=1024, far below bf16 rounding).
__global__ void gen_kernel(const float* __restrict__ times,
                           const float* __restrict__ type_emb,
                           ushort_t* __restrict__ emb,
                           ushort_t* __restrict__ embT) {
    __shared__ float s_tm[64];
    __shared__ float s_te[DD];
    const int bid = blockIdx.x;
    const int b = bid >> 6;
    const int ntile = bid & 63;            // 64-n tile; t = ntile>>5
    const int t = ntile >> 5;
    const int l0 = (ntile & 31) * 64;
    const int tid = threadIdx.x;           // 256

    if (tid < 64) s_tm[tid] = times[(size_t)(t * BB + b) * LL + l0 + tid];
    s_te[tid]       = type_emb[t * DD + tid];
    s_te[tid + 256] = type_emb[t * DD + tid + 256];
    __syncthreads();

    // ---- phase A: emb rows. thread -> (row = i*32 + tid>>3, d-chunks)
    {
        const int rsub = tid >> 3;
        const int coff = (tid & 7) * 8;
#pragma unroll
        for (int i = 0; i < 2; ++i) {
            const int rr = i * 32 + rsub;          // 0..63 in tile
            const float tm = s_tm[rr];
            const float pad = (tm != 0.0f) ? 1.0f : 0.0f;
            ushort_t* dst = emb + ((size_t)b * NN + (size_t)ntile * 64 + rr) * DD;
#pragma unroll
            for (int k = 0; k < 8; ++k) {
                const int d0 = k * 64 + coff;
                union { ushort_t us[8]; short8 v; } o;
#pragma unroll
                for (int j = 0; j < 4; ++j) {
                    const float th = tm * inv_pos_f((d0 >> 1) + j);
                    const float sv = __sinf(th);
                    const float cv = __cosf(th);
                    o.us[2 * j]     = f2b((sv + s_te[d0 + 2 * j]) * pad);
                    o.us[2 * j + 1] = f2b((cv + s_te[d0 + 2 * j + 1]) * pad);
                }
                *reinterpret_cast<short8*>(dst + d0) = o.v;
            }
        }
    }

    // ---- phase B: embT rows. thread -> (d = pass*32 + tid>>3, 8 n's)
    {
        const int dsub = tid >> 3;
        const int nc = (tid & 7) * 8;
#pragma unroll 4
        for (int pass = 0; pass < 16; ++pass) {
            const int d = pass * 32 + dsub;
            const float ip = inv_pos_f(d >> 1);
            const float te = s_te[d];
            const bool use_cos = (d & 1);
            union { ushort_t us[8]; short8 v; } o;
#pragma unroll
            for (int j = 0; j < 8; ++j) {
                const float tm = s_tm[nc + j];
                const float th = tm * ip;
                const float v = use_cos ? __cosf(th) : __sinf(th);
                o.us[j] = f2b((v + te) * ((tm != 0.0f) ? 1.0f : 0.0f));
            }
            *reinterpret_cast<short8*>(
                embT + ((size_t)b * DD + d) * NN + (size_t)ntile * 64 + nc) = o.v;
        }
    }
}

// ---------------- q table (bf16, pre-scaled): q'[g][d] ----------------
__global__ void qb_kernel(ushort_t* __restrict__ qb) {
    const int g = blockIdx.x;
    const int tid = threadIdx.x;  // 128
    const float mid = (float)g + 0.5f;
#pragma unroll
    for (int i = 0; i < 4; ++i) {
        int d = i * 128 + tid;
        float theta = mid * inv_pos_f(d >> 1);
        float v = (d & 1) ? cosf(theta) : sinf(theta);
        qb[(size_t)g * DD + d] = f2b(v * QSCL);
    }
}

// ---------------- flash attention, fixed-shift softmax ----------------
// P = exp2(s' - 4): scores provably bounded (|s'| <= ~73 << fp32 exp range),
// so no max-reduce / rescale / cross-iter state. l accumulates in registers.
// SPLIT: block handles one t-half, writes partial O (raw) + l to ws.
template <bool SPLIT>
__global__ __launch_bounds__(256, 2)
void attn2(const ushort_t* __restrict__ emb,
           const ushort_t* __restrict__ embT,
           const ushort_t* __restrict__ qb,
           const int* __restrict__ real_len,
           float* __restrict__ outp,          // SPLIT ? partial O : final out
           float* __restrict__ lpart) {       // SPLIT only
    __shared__ __align__(16) ushort_t sA[32 * 520];  // emb tile, row stride 1040B
    __shared__ __align__(16) ushort_t sP[32 * 40];   // P [g][n], row stride 80B
    __shared__ float s_lred[2][32];

    const int idx = blockIdx.x;               // low 3 bits = XCD slot = b%8
    const int xcd = idx & 7;
    const int gt = (idx >> 3) & 31;
    int b, s;
    if (SPLIT) { s = (idx >> 8) & 1; b = xcd + ((idx >> 9) << 3); }
    else       { s = 0;              b = xcd + ((idx >> 8) << 3); }
    const int g0 = gt * 32;

    const int tid = threadIdx.x;              // 256
    const int lane = tid & 63;
    const int w = tid >> 6;                   // 4 waves
    const int l15 = lane & 15;
    const int quad = lane >> 4;               // 0..3
    const int mt1 = w >> 1;                   // GEMM1 n-tile (0/1)
    const int gt1 = w & 1;                    // GEMM1 g-tile (0/1)

    // q B-fragments resident: lane holds q'[g0+gt1*16+l15][kc*32+quad*8+j]
    short8 qf[16];
    {
        const ushort_t* qrow = qb + (size_t)(g0 + gt1 * 16 + l15) * DD + quad * 8;
#pragma unroll
        for (int kc = 0; kc < 16; ++kc)
            qf[kc] = *reinterpret_cast<const short8*>(qrow + kc * 32);
    }

    const ushort_t* embB  = emb  + (size_t)b * NN * DD;
    const ushort_t* embTB = embT + (size_t)b * DD * NN;

    const int rl0 = real_len[b];
    const int rl1 = real_len[BB + b];
    int first, count;
    const int e0 = (rl0 + 31) >> 5;
    if (SPLIT) {
        if (s == 0) { first = 0;  count = e0; }
        else        { first = 64; count = (rl1 + 31) >> 5; }
    } else {
        first = 0; count = e0 + ((rl1 + 31) >> 5);
    }

    f32x4 accO[8][2];
#pragma unroll
    for (int i = 0; i < 8; ++i) { accO[i][0] = (f32x4)0.f; accO[i][1] = (f32x4)0.f; }
    float ls = 0.f;   // per-lane l partial for column (gt1*16+l15), rows of mt1-half

    // async stage one 32x512 emb tile; wave stages rows w*8..w*8+7
    auto stage = [&](int nt) {
        const ushort_t* src = embB + (size_t)(nt * 32 + w * 8) * DD + lane * 8;
        ushort_t* dst = sA + (w * 8) * 520;
#pragma unroll
        for (int i = 0; i < 8; ++i) {
            __builtin_amdgcn_global_load_lds(
                (const __attribute__((address_space(1))) unsigned int*)(src + (size_t)i * DD),
                (__attribute__((address_space(3))) unsigned int*)(dst + i * 520),
                16, 0, 0);
        }
    };
    // embT A-fragments for GEMM2, prefetched into regs one tile ahead
    short8 tf[8];
    auto prefetchT = [&](int nt) {
        const ushort_t* trow = embTB + (size_t)(w * 128 + l15) * NN + nt * 32 + quad * 8;
#pragma unroll
        for (int mt = 0; mt < 8; ++mt)
            tf[mt] = *reinterpret_cast<const short8*>(trow + (size_t)mt * 16 * NN);
    };

    int cur = first;
    stage(cur);
    prefetchT(cur);

    for (int k = 0; k < count; ++k) {
        int nxt;
        if (SPLIT) nxt = cur + 1;
        else       nxt = (cur + 1 == e0) ? 64 : cur + 1;

        __syncthreads();   // B1: sA staged + tf loaded (vmcnt drain), sP consumed

        // ---- GEMM1: two independent 8-MFMA chains
        f32x4 S0 = (f32x4)0.f, S1 = (f32x4)0.f;
        {
            const ushort_t* arow = sA + (mt1 * 16 + l15) * 520 + quad * 8;
#pragma unroll
            for (int kc = 0; kc < 8; ++kc) {
                short8 a0 = *reinterpret_cast<const short8*>(arow + (2 * kc) * 32);
                short8 a1 = *reinterpret_cast<const short8*>(arow + (2 * kc + 1) * 32);
                S0 = __builtin_amdgcn_mfma_f32_16x16x32_bf16(a0, qf[2 * kc],     S0, 0, 0, 0);
                S1 = __builtin_amdgcn_mfma_f32_16x16x32_bf16(a1, qf[2 * kc + 1], S1, 0, 0, 0);
            }
        }

        // ---- mask + fixed-shift exp2; accumulate l in regs; pack P to LDS
        const int n0 = cur * 32;
        const int nb = n0 + mt1 * 16 + quad * 4;
        const int rl = (nb >= LL) ? rl1 : rl0;
        const int lb = nb & (LL - 1);
        float p[4];
#pragma unroll
        for (int r = 0; r < 4; ++r)
            p[r] = (lb + r < rl) ? exp2f(S0[r] + S1[r] - 4.0f) : 0.0f;
        ls += (p[0] + p[1]) + (p[2] + p[3]);
        {
            union { unsigned short us[4]; unsigned long long u64; } pk;
            pk.us[0] = f2b(p[0]); pk.us[1] = f2b(p[1]); pk.us[2] = f2b(p[2]); pk.us[3] = f2b(p[3]);
            *reinterpret_cast<unsigned long long*>(
                sP + (gt1 * 16 + l15) * 40 + mt1 * 16 + quad * 4) = pk.u64;
        }
        __syncthreads();   // B2: sP ready, sA reads done

        if (k + 1 < count) stage(nxt);        // DMA overlaps GEMM2 + next GEMM1

        // ---- GEMM2: A = tf regs (prefetched), B = P from LDS
        {
            short8 bP0 = *reinterpret_cast<const short8*>(sP + l15 * 40 + quad * 8);
            short8 bP1 = *reinterpret_cast<const short8*>(sP + (16 + l15) * 40 + quad * 8);
#pragma unroll
            for (int mt = 0; mt < 8; ++mt) {
                accO[mt][0] = __builtin_amdgcn_mfma_f32_16x16x32_bf16(tf[mt], bP0, accO[mt][0], 0, 0, 0);
                accO[mt][1] = __builtin_amdgcn_mfma_f32_16x16x32_bf16(tf[mt], bP1, accO[mt][1], 0, 0, 0);
            }
        }
        if (k + 1 < count) prefetchT(nxt);    // WAR on tf resolves at issue
        cur = nxt;
    }

    // ---- l reduction: quads via shfl, mt1 halves via LDS
    ls += __shfl_xor(ls, 16, 64);
    ls += __shfl_xor(ls, 32, 64);
    if (lane < 16) s_lred[mt1][gt1 * 16 + lane] = ls;
    __syncthreads();

    if (SPLIT) {
        if (w == 0 && lane < 32)
            lpart[((size_t)s * BB + b) * GG + g0 + lane] = s_lred[0][lane] + s_lred[1][lane];
        float* po = outp + (((size_t)s * BB + b) * GG) * DD;
#pragma unroll
        for (int mt = 0; mt < 8; ++mt) {
#pragma unroll
            for (int gtt = 0; gtt < 2; ++gtt) {
                float4 v;
                v.x = accO[mt][gtt][0]; v.y = accO[mt][gtt][1];
                v.z = accO[mt][gtt][2]; v.w = accO[mt][gtt][3];
                const int g = g0 + gtt * 16 + l15;
                const int d = w * 128 + mt * 16 + quad * 4;
                *reinterpret_cast<float4*>(po + (size_t)g * DD + d) = v;
            }
        }
    } else {
        const float il0 = 1.f / (s_lred[0][l15] + s_lred[1][l15]);
        const float il1 = 1.f / (s_lred[0][16 + l15] + s_lred[1][16 + l15]);
#pragma unroll
        for (int mt = 0; mt < 8; ++mt) {
#pragma unroll
            for (int gtt = 0; gtt < 2; ++gtt) {
                const float il = gtt ? il1 : il0;
                float4 v;
                v.x = accO[mt][gtt][0] * il; v.y = accO[mt][gtt][1] * il;
                v.z = accO[mt][gtt][2] * il; v.w = accO[mt][gtt][3] * il;
                const int g = g0 + gtt * 16 + l15;
                const int d = w * 128 + mt * 16 + quad * 4;
                *reinterpret_cast<float4*>(outp + ((size_t)b * GG + g) * DD + d) = v;
            }
        }
    }
}

// ---------------- combine (split path): out = (O0+O1)/(l0+l1) ----------------
__global__ void combine_kernel(const float* __restrict__ pO,
                               const float* __restrict__ pl,
                               float* __restrict__ out) {
    const size_t i4 = (size_t)blockIdx.x * 256 + threadIdx.x;  // 0..2M-1
    const size_t base = i4 * 4;
    const size_t bg = base >> 9;                               // (b*G+g)
    const float inv = 1.0f / (pl[bg] + pl[(size_t)BB * GG + bg]);
    const float4 a = *reinterpret_cast<const float4*>(pO + base);
    const float4 c = *reinterpret_cast<const float4*>(pO + (size_t)BB * GG * DD + base);
    float4 o;
    o.x = (a.x + c.x) * inv; o.y = (a.y + c.y) * inv;
    o.z = (a.z + c.z) * inv; o.w = (a.w + c.w) * inv;
    *reinterpret_cast<float4*>(out + base) = o;
}

// ---------------- round-2 proven fallback (tiny ws) ----------------
__global__ void emb_kernel(const float* __restrict__ times,
                           const float* __restrict__ type_emb,
                           ushort_t* __restrict__ emb) {
    const int row = blockIdx.x;
    const int b = row >> 12;
    const int n = row & (NN - 1);
    const int t = n >> 11;
    const int l = n & (LL - 1);
    const float tm = times[(size_t)(t * BB + b) * LL + l];
    const float pad = (tm != 0.0f) ? 1.0f : 0.0f;
    const int tid = threadIdx.x;
#pragma unroll
    for (int i = 0; i < 2; ++i) {
        int d = i * 256 + tid;
        float theta = tm * inv_pos_f(d >> 1);
        float v = (d & 1) ? cosf(theta) : sinf(theta);
        v = (v + type_emb[t * DD + d]) * pad;
        emb[(size_t)row * DD + d] = f2b(v);
    }
}
__global__ void qgrid_kernel(float* __restrict__ qbuf) {
    const int g = blockIdx.x;
    const int tid = threadIdx.x;
    const float mid = (float)g + 0.5f;
#pragma unroll
    for (int i = 0; i < 4; ++i) {
        int d = i * 128 + tid;
        float theta = mid * inv_pos_f(d >> 1);
        float v = (d & 1) ? cosf(theta) : sinf(theta);
        qbuf[(size_t)g * DD + d] = v;
    }
}
__global__ void attn_kernel(const ushort_t* __restrict__ emb,
                            const float* __restrict__ qbuf,
                            const int* __restrict__ real_len,
                            float* __restrict__ out) {
    __shared__ float s_lds[NN];
    __shared__ float q_s[DD];
    __shared__ float red[8];
    const int blk = blockIdx.x;
    const int b = blk >> 10;
    const int g = blk & (GG - 1);
    const int tid = threadIdx.x;
    const int lane = tid & 63;
    const int wave = tid >> 6;
    q_s[tid]       = qbuf[(size_t)g * DD + tid];
    q_s[tid + 256] = qbuf[(size_t)g * DD + tid + 256];
    __syncthreads();
    float qr[8];
#pragma unroll
    for (int j = 0; j < 8; ++j) qr[j] = q_s[lane * 8 + j];
    const unsigned int* embB =
        reinterpret_cast<const unsigned int*>(emb) + (size_t)b * NN * (DD / 2);
#pragma unroll 2
    for (int it = 0; it < NN / 4; ++it) {
        const int n = it * 4 + wave;
        const uint4 raw = *reinterpret_cast<const uint4*>(embB + (size_t)n * (DD / 2) + lane * 4);
        float sacc = 0.f;
        sacc = fmaf(__uint_as_float(raw.x << 16),         qr[0], sacc);
        sacc = fmaf(__uint_as_float(raw.x & 0xffff0000u), qr[1], sacc);
        sacc = fmaf(__uint_as_float(raw.y << 16),         qr[2], sacc);
        sacc = fmaf(__uint_as_float(raw.y & 0xffff0000u), qr[3], sacc);
        sacc = fmaf(__uint_as_float(raw.z << 16),         qr[4], sacc);
        sacc = fmaf(__uint_as_float(raw.z & 0xffff0000u), qr[5], sacc);
        sacc = fmaf(__uint_as_float(raw.w << 16),         qr[6], sacc);
        sacc = fmaf(__uint_as_float(raw.w & 0xffff0000u), qr[7], sacc);
#pragma unroll
        for (int off = 32; off; off >>= 1) sacc += __shfl_xor(sacc, off, 64);
        if (lane == 0) s_lds[n] = sacc * SCALE;
    }
    __syncthreads();
    const int rl0 = real_len[b];
    const int rl1 = real_len[BB + b];
    float m = -INFINITY;
    float sv[16];
#pragma unroll
    for (int i = 0; i < 16; ++i) {
        const int n = i * 256 + tid;
        float sc = s_lds[n];
        const int l = n & (LL - 1);
        const bool valid = l < ((n < LL) ? rl0 : rl1);
        sc = valid ? sc : -INFINITY;
        sv[i] = sc;
        m = fmaxf(m, sc);
    }
#pragma unroll
    for (int off = 32; off; off >>= 1) m = fmaxf(m, __shfl_xor(m, off, 64));
    if (lane == 0) red[wave] = m;
    __syncthreads();
    m = fmaxf(fmaxf(red[0], red[1]), fmaxf(red[2], red[3]));
    float lsum = 0.f;
#pragma unroll
    for (int i = 0; i < 16; ++i) {
        const int n = i * 256 + tid;
        const float e = expf(sv[i] - m);
        s_lds[n] = e;
        lsum += e;
    }
#pragma unroll
    for (int off = 32; off; off >>= 1) lsum += __shfl_xor(lsum, off, 64);
    if (lane == 0) red[4 + wave] = lsum;
    __syncthreads();
    const float inv_l = 1.0f / (red[4] + red[5] + red[6] + red[7]);
    float acc[8] = {0.f, 0.f, 0.f, 0.f, 0.f, 0.f, 0.f, 0.f};
#pragma unroll 2
    for (int kk = 0; kk < NN / 4; ++kk) {
        const int n = kk * 4 + wave;
        const float p = s_lds[n];
        const uint4 raw = *reinterpret_cast<const uint4*>(embB + (size_t)n * (DD / 2) + lane * 4);
        acc[0] = fmaf(p, __uint_as_float(raw.x << 16),         acc[0]);
        acc[1] = fmaf(p, __uint_as_float(raw.x & 0xffff0000u), acc[1]);
        acc[2] = fmaf(p, __uint_as_float(raw.y << 16),         acc[2]);
        acc[3] = fmaf(p, __uint_as_float(raw.y & 0xffff0000u), acc[3]);
        acc[4] = fmaf(p, __uint_as_float(raw.z << 16),         acc[4]);
        acc[5] = fmaf(p, __uint_as_float(raw.z & 0xffff0000u), acc[5]);
        acc[6] = fmaf(p, __uint_as_float(raw.w << 16),         acc[6]);
        acc[7] = fmaf(p, __uint_as_float(raw.w & 0xffff0000u), acc[7]);
    }
    __syncthreads();
    *reinterpret_cast<float4*>(&s_lds[wave * DD + lane * 8])     = make_float4(acc[0], acc[1], acc[2], acc[3]);
    *reinterpret_cast<float4*>(&s_lds[wave * DD + lane * 8 + 4]) = make_float4(acc[4], acc[5], acc[6], acc[7]);
    __syncthreads();
    {
        const int d0 = tid * 2;
        const float o0 = (s_lds[d0]     + s_lds[DD + d0]     + s_lds[2 * DD + d0]     + s_lds[3 * DD + d0])     * inv_l;
        const float o1 = (s_lds[d0 + 1] + s_lds[DD + d0 + 1] + s_lds[2 * DD + d0 + 1] + s_lds[3 * DD + d0 + 1]) * inv_l;
        *reinterpret_cast<float2*>(out + (size_t)blk * DD + d0) = make_float2(o0, o1);
    }
}

extern "C" void kernel_launch(void* const* d_in, const int* in_sizes, int n_in,
                              void* d_out, int out_size, void* d_ws, size_t ws_size,
                              hipStream_t stream) {
    const float* times    = (const float*)d_in[0];
    const float* type_emb = (const float*)d_in[1];
    const int*   real_len = (const int*)d_in[2];
    float* out = (float*)d_out;

    const size_t embBytes = (size_t)BB * NN * DD * sizeof(ushort_t);   // 64 MB
    const size_t qbBytes  = (size_t)GG * DD * sizeof(ushort_t);        // 1 MB
    const size_t pOBytes  = (size_t)2 * BB * GG * DD * sizeof(float);  // 64 MB
    const size_t plBytes  = (size_t)2 * BB * GG * sizeof(float);       // 128 KB
    const size_t needFast  = 2 * embBytes + qbBytes;                   // ~129 MB
    const size_t needSplit = needFast + pOBytes + plBytes;             // ~194 MB

    ushort_t* emb = (ushort_t*)d_ws;

    if (ws_size >= needFast) {
        ushort_t* embT = (ushort_t*)((char*)d_ws + embBytes);
        ushort_t* qb   = (ushort_t*)((char*)d_ws + 2 * embBytes);
        gen_kernel<<<BB * 64, 256, 0, stream>>>(times, type_emb, emb, embT);
        qb_kernel<<<GG, 128, 0, stream>>>(qb);
        if (ws_size >= needSplit) {
            float* pO = (float*)((char*)d_ws + needFast);
            float* pl = (float*)((char*)d_ws + needFast + pOBytes);
            attn2<true><<<2 * BB * 32, 256, 0, stream>>>(emb, embT, qb, real_len, pO, pl);
            combine_kernel<<<(BB * GG * DD) / (256 * 4), 256, 0, stream>>>(pO, pl, out);
        } else {
            attn2<false><<<BB * 32, 256, 0, stream>>>(emb, embT, qb, real_len, out, nullptr);
        }
    } else {
        // fallback: 66 MB footprint (proven in round 2)
        float* qbuf = (float*)((char*)d_ws + embBytes);
        emb_kernel<<<BB * NN, 256, 0, stream>>>(times, type_emb, emb);
        qgrid_kernel<<<GG, 128, 0, stream>>>(qbuf);
        attn_kernel<<<BB * GG, 256, 0, stream>>>(emb, qbuf, real_len, out);
    }
}